// Round 4
// baseline (481.992 us; speedup 1.0000x reference)
//
#include <hip/hip_runtime.h>
#include <hip/hip_fp16.h>
#include <math.h>
#include <stdint.h>
#include <type_traits>

#define NN   100000
#define EE   1200000
#define GG   128
#define FIN  16
#define HH   64
#define OUTF 5
#define NHID 3

#define CE   4096                       // edges per block in bucket phases
#define EB   ((EE + CE - 1) / CE)       // 293 edge-blocks
#define NBUK ((NN + 511) >> 9)          // 196 buckets of 512 nodes
#define LEN  (NBUK * EB)                // hblk/eoff length

#define SRCMASK 0x03FFFFFFu             // low 26 bits of packed col entry

typedef _Float16 f16x8 __attribute__((ext_vector_type(8)));
typedef _Float16 f16x4 __attribute__((ext_vector_type(4)));
typedef _Float16 f16x2 __attribute__((ext_vector_type(2)));
typedef float f32x4 __attribute__((ext_vector_type(4)));

#if defined(__has_builtin)
#if __has_builtin(__builtin_amdgcn_fdot2)
#define HAVE_FDOT2 1
#endif
#endif

static __device__ __forceinline__ float dot8_f16(f16x8 a, f16x8 b) {
#ifdef HAVE_FDOT2
  float ds = 0.f;
#pragma unroll
  for (int u = 0; u < 4; u++) {
    f16x2 x = {a[2 * u], a[2 * u + 1]};
    f16x2 y = {b[2 * u], b[2 * u + 1]};
    ds = __builtin_amdgcn_fdot2(x, y, ds, false);
  }
  return ds;
#else
  float ds = 0.f;
#pragma unroll
  for (int u = 0; u < 8; u++) ds += (float)a[u] * (float)b[u];
  return ds;
#endif
}

// ---------------- wave helpers ----------------
static __device__ __forceinline__ float wave_reduce_sum(float p) {
#pragma unroll
  for (int m = 32; m >= 1; m >>= 1) p += __shfl_xor(p, m, 64);
  return p;
}

// ---------------- bucketed CSR build ----------------
__global__ void k_bh(const int* __restrict__ ei, int* __restrict__ hblk) {
  __shared__ int h[NBUK];
  int tid = threadIdx.x, blk = blockIdx.x;
  for (int i = tid; i < NBUK; i += 256) h[i] = 0;
  __syncthreads();
  int base = blk * CE;
  for (int i = tid; i < CE; i += 256) {
    int e = base + i;
    if (e < EE) atomicAdd(&h[ei[EE + e] >> 9], 1);
  }
  __syncthreads();
  for (int i = tid; i < NBUK; i += 256) hblk[i * EB + blk] = h[i];
}

__global__ void k_scan1(const int* __restrict__ in, int* __restrict__ incl,
                        int* __restrict__ bsum, int n) {
  __shared__ int sd[256];
  int t = threadIdx.x, blk = blockIdx.x;
  int base = blk * 1024 + t * 4;
  int v[4];
#pragma unroll
  for (int i = 0; i < 4; i++) v[i] = (base + i < n) ? in[base + i] : 0;
  int s = v[0] + v[1] + v[2] + v[3];
  sd[t] = s;
  __syncthreads();
  for (int off = 1; off < 256; off <<= 1) {
    int x = 0;
    if (t >= off) x = sd[t - off];
    __syncthreads();
    if (t >= off) sd[t] += x;
    __syncthreads();
  }
  int run = sd[t] - s;
#pragma unroll
  for (int i = 0; i < 4; i++) {
    run += v[i];
    if (base + i < n) incl[base + i] = run;
  }
  if (t == 255) bsum[blk] = sd[255];
}

__global__ void k_scan2(const int* __restrict__ bsum, int* __restrict__ boff, int nb) {
  if (threadIdx.x == 0 && blockIdx.x == 0) {
    int run = 0;
    for (int i = 0; i < nb; i++) { boff[i] = run; run += bsum[i]; }
  }
}

__global__ void k_eoff(const int* __restrict__ incl, const int* __restrict__ boff,
                       const int* __restrict__ hblk, int* __restrict__ eoff, int n) {
  int t = blockIdx.x * blockDim.x + threadIdx.x;
  if (t < n) eoff[t] = incl[t] + boff[t / 1024] - hblk[t];
}

__global__ void k_binwrite(const int* __restrict__ ei, const int* __restrict__ eoff,
                           int2* __restrict__ ebuf) {
  __shared__ int cur[NBUK];
  int tid = threadIdx.x, blk = blockIdx.x;
  for (int i = tid; i < NBUK; i += 256) cur[i] = eoff[i * EB + blk];
  __syncthreads();
  int base = blk * CE;
  for (int i = tid; i < CE; i += 256) {
    int e = base + i;
    if (e < EE) {
      int d = ei[EE + e];
      int s = ei[e];
      int p = atomicAdd(&cur[d >> 9], 1);
      ebuf[p] = make_int2(s, d);
    }
  }
}

// merged bdeg2 + binscatter: histogram -> scan -> row_ptr -> cursors ->
// scatter col. R19: col entry packs dst-local (dst&63, valid because fused
// blocks are 64-aligned) into bits 26..31; src (<2^26) in low bits.
__global__ void k_bcsr(const int2* __restrict__ ebuf, const int* __restrict__ eoff,
                       int* __restrict__ row_ptr, int* __restrict__ col, int n) {
  __shared__ int dl[512];
  __shared__ int ps[256];
  int b = blockIdx.x, tid = threadIdx.x;
  int d0 = b << 9;
  dl[tid] = 0; dl[tid + 256] = 0;
  __syncthreads();
  int s0 = eoff[b * EB];
  int s1 = (b + 1 < NBUK) ? eoff[(b + 1) * EB] : EE;
  for (int e = s0 + tid; e < s1; e += 256) atomicAdd(&dl[ebuf[e].y - d0], 1);
  __syncthreads();
  int a0 = dl[2 * tid], a1 = dl[2 * tid + 1];
  ps[tid] = a0 + a1;
  __syncthreads();
  for (int off = 1; off < 256; off <<= 1) {
    int x = 0;
    if (tid >= off) x = ps[tid - off];
    __syncthreads();
    if (tid >= off) ps[tid] += x;
    __syncthreads();
  }
  int epair = ps[tid] - (a0 + a1);     // exclusive prefix of this pair
  int r0 = s0 + epair;
  int r1 = r0 + a0;
  int i0 = d0 + 2 * tid;
  if (i0 <= n) row_ptr[i0] = r0;       // covers row_ptr[n] = EE
  if (i0 + 1 <= n) row_ptr[i0 + 1] = r1;
  __syncthreads();
  dl[2 * tid] = r0;                    // reuse histogram LDS as cursors
  dl[2 * tid + 1] = r1;
  __syncthreads();
  for (int e = s0 + tid; e < s1; e += 256) {
    int2 sd = ebuf[e];
    int p = atomicAdd(&dl[sd.y - d0], 1);
    col[p] = (int)(((unsigned)sd.x) | (((unsigned)sd.y & 63u) << 26));
  }
}

// ---------------- projections via MFMA ----------------
// R19: operands swapped (mfma(bf, af) computes D^T) so each lane holds 4
// CONSECUTIVE output columns -> 16x 8B stores/lane instead of 64x 2B.
template <int F, typename TIN>
__global__ __launch_bounds__(256) void k_gemm_mfma(
    const TIN* __restrict__ X,
    const float* __restrict__ Wq, const float* __restrict__ bq,
    const float* __restrict__ Wk, const float* __restrict__ bk,
    const float* __restrict__ Wv, const float* __restrict__ bv,
    const float* __restrict__ Ws, const float* __restrict__ bs,
    __half* __restrict__ qh, __half* __restrict__ kh, __half* __restrict__ vh,
    __half* __restrict__ Bh, int n) {
  constexpr int KH = (F + 31) / 32;
  constexpr int S = KH * 32 + 8;
  __shared__ _Float16 xs[64 * S];
  int tid = threadIdx.x;
  int lane = tid & 63;
  int wv = tid >> 6;
  int quad = lane >> 4;
  int li = lane & 15;
  int node0 = blockIdx.x * 64;

  if constexpr (std::is_same<TIN, float>::value) {
    constexpr int F4 = F / 4;
    constexpr int CNT = 64 * F4 / 256;
#pragma unroll
    for (int i = 0; i < CNT; i++) {
      int idx = tid + i * 256;
      int nd = idx / F4;
      int kb = (idx % F4) * 4;
      float4 p;
      if (node0 + nd < n) p = *(const float4*)(X + (size_t)(node0 + nd) * F + kb);
      else p = make_float4(0.f, 0.f, 0.f, 0.f);
      _Float16* d = xs + nd * S + kb;
      d[0] = (_Float16)p.x; d[1] = (_Float16)p.y;
      d[2] = (_Float16)p.z; d[3] = (_Float16)p.w;
    }
    if (F == 16) {  // zero-pad k in [16,32)
      int nd = tid >> 2;
      int kb = 16 + (tid & 3) * 4;
      _Float16* d = xs + nd * S + kb;
      d[0] = 0; d[1] = 0; d[2] = 0; d[3] = 0;
    }
  } else {
    constexpr int F8 = F / 8;
    constexpr int CNT = 64 * F8 / 256;
#pragma unroll
    for (int i = 0; i < CNT; i++) {
      int idx = tid + i * 256;
      int nd = idx / F8;
      int kb = (idx % F8) * 8;
      f16x8 p = {};
      if (node0 + nd < n)
        p = *(const f16x8*)((const _Float16*)X + (size_t)(node0 + nd) * F + kb);
      *(f16x8*)(xs + nd * S + kb) = p;
    }
  }

  const float* W; const float* bias;
  if (wv == 0)      { W = Wq; bias = bq; }
  else if (wv == 1) { W = Wk; bias = bk; }
  else if (wv == 2) { W = Wv; bias = bv; }
  else              { W = Ws; bias = bs; }

  f16x8 bf[4][KH];
#pragma unroll
  for (int ns = 0; ns < 4; ns++)
#pragma unroll
    for (int kh2 = 0; kh2 < KH; kh2++)
#pragma unroll
      for (int j = 0; j < 8; j++) {
        int kidx = kh2 * 32 + quad * 8 + j;
        bf[ns][kh2][j] = (kidx < F)
            ? (_Float16)W[(size_t)kidx * 64 + ns * 16 + li] : (_Float16)0.f;
      }
  // bias for the 4 consecutive cols this lane owns per ns-tile
  f32x4 bv4[4];
#pragma unroll
  for (int ns = 0; ns < 4; ns++)
    bv4[ns] = *(const f32x4*)(bias + ns * 16 + quad * 4);

  __syncthreads();

  f16x8 af[4][KH];
#pragma unroll
  for (int ms = 0; ms < 4; ms++)
#pragma unroll
    for (int kh2 = 0; kh2 < KH; kh2++)
      af[ms][kh2] = *(const f16x8*)(xs + (ms * 16 + li) * S + kh2 * 32 + quad * 8);

  f32x4 acc[4][4];
#pragma unroll
  for (int ms = 0; ms < 4; ms++)
#pragma unroll
    for (int ns = 0; ns < 4; ns++) acc[ms][ns] = bv4[ns];
#pragma unroll
  for (int kh2 = 0; kh2 < KH; kh2++)
#pragma unroll
    for (int ms = 0; ms < 4; ms++)
#pragma unroll
      for (int ns = 0; ns < 4; ns++)
        acc[ms][ns] = __builtin_amdgcn_mfma_f32_16x16x32_f16(
            bf[ns][kh2], af[ms][kh2], acc[ms][ns], 0, 0, 0);

  __half* outh = (wv == 0) ? qh : (wv == 1) ? kh : (wv == 2) ? vh : Bh;
#pragma unroll
  for (int ms = 0; ms < 4; ms++) {
    int node = node0 + ms * 16 + li;
    if (node < n) {
#pragma unroll
      for (int ns = 0; ns < 4; ns++) {
        f16x4 o = {(_Float16)acc[ms][ns][0], (_Float16)acc[ms][ns][1],
                   (_Float16)acc[ms][ns][2], (_Float16)acc[ms][ns][3]};
        *(f16x4*)((_Float16*)outh + (size_t)node * 64 + ns * 16 + quad * 4) = o;
      }
    }
  }
}

// ---------------- fused attention, two internal phases (R19) ----------------
// Block = 64 consecutive dsts, chunked at 1024 edges. col entries carry the
// dst-local index in bits 26..31 (k_bcsr) -> phase A needs NO search.
// ws[i] packs (colval, weight) so phase B reads one b64 per edge.
// Phase A: 32 groups x 8 lanes, fdot2 dot, 3 shfl reduce, exp -> ws[i].y.
// Phase B: 8 groups x 32 lanes, register accumulators, coalesced v rows.
__global__ __launch_bounds__(256) void k_fused(
    const __half* __restrict__ qh, const __half* __restrict__ kh,
    const __half* __restrict__ vh, const int* __restrict__ row_ptr,
    const int* __restrict__ col, __half* __restrict__ Bh, int n) {
  __shared__ int2 ws[1024];            // .x = packed col, .y = weight bits
  __shared__ int rpl[65];
  int tid = threadIdx.x;
  int d0 = blockIdx.x * 64;
  int ndst = n - d0; if (ndst > 64) ndst = 64;

  if (tid < 65) {
    int dd = d0 + tid; if (dd > n) dd = n;
    rpl[tid] = row_ptr[dd];
  }
  __syncthreads();
  int e0 = rpl[0], e1 = rpl[ndst];

  int gid = tid >> 5, hl = tid & 31;   // phase B: 8 groups x 32 lanes
  int ag = tid >> 3, aj = tid & 7;     // phase A: 32 groups x 8 lanes

  float2 acc[8];
  float den[8];
#pragma unroll
  for (int k = 0; k < 8; k++) { acc[k] = make_float2(0.f, 0.f); den[k] = 0.f; }

  for (int c0 = e0; c0 < e1; c0 += 1024) {
    int cn = e1 - c0; if (cn > 1024) cn = 1024;
    // stage col chunk (coalesced)
#pragma unroll
    for (int s = 0; s < 4; s++) {
      int i = tid + s * 256;
      if (i < cn) ws[i].x = col[c0 + i];
    }
    __syncthreads();

    // ---- phase A: scores ----
    for (int i = ag; i < cn; i += 32) {
      unsigned v = (unsigned)ws[i].x;
      int src = (int)(v & SRCMASK);
      int dl = (int)(v >> 26);
      f16x8 kv = *(const f16x8*)((const _Float16*)kh + (size_t)src * 64 + aj * 8);
      f16x8 qv = *(const f16x8*)((const _Float16*)qh + (size_t)(d0 + dl) * 64 + aj * 8);
      float ds = dot8_f16(qv, kv);
      ds += __shfl_xor(ds, 1, 64);
      ds += __shfl_xor(ds, 2, 64);
      ds += __shfl_xor(ds, 4, 64);
      if (aj == 0)
        ws[i].y = __float_as_int(__expf(fminf(ds * 0.125f, 60.f)));  // 1/sqrt(64)
    }
    __syncthreads();

    // ---- phase B: aggregate; group gid owns dsts gid*8 .. gid*8+7 ----
#pragma unroll
    for (int k = 0; k < 8; k++) {
      int dl = gid * 8 + k;
      if (dl < ndst) {
        int lo2 = rpl[dl];     if (lo2 < c0) lo2 = c0;
        int hi2 = rpl[dl + 1]; if (hi2 > c0 + cn) hi2 = c0 + cn;
        int i = lo2 - c0, iend = hi2 - c0;
        for (; i + 2 <= iend; i += 2) {
          int2 p0 = ws[i], p1 = ws[i + 1];
          float w0 = __int_as_float(p0.y); int s0 = p0.x & (int)SRCMASK;
          float w1 = __int_as_float(p1.y); int s1 = p1.x & (int)SRCMASK;
          float2 f0 = __half22float2(*(const __half2*)(vh + (size_t)s0 * 64 + hl * 2));
          float2 f1 = __half22float2(*(const __half2*)(vh + (size_t)s1 * 64 + hl * 2));
          acc[k].x = fmaf(w0, f0.x, acc[k].x); acc[k].y = fmaf(w0, f0.y, acc[k].y);
          acc[k].x = fmaf(w1, f1.x, acc[k].x); acc[k].y = fmaf(w1, f1.y, acc[k].y);
          den[k] += w0 + w1;
        }
        if (i < iend) {
          int2 p0 = ws[i];
          float w0 = __int_as_float(p0.y); int s0 = p0.x & (int)SRCMASK;
          float2 f0 = __half22float2(*(const __half2*)(vh + (size_t)s0 * 64 + hl * 2));
          acc[k].x = fmaf(w0, f0.x, acc[k].x); acc[k].y = fmaf(w0, f0.y, acc[k].y);
          den[k] += w0;
        }
      }
    }
    __syncthreads();   // before next chunk overwrites ws
  }

  // write out (B pre-holds the skip term)
#pragma unroll
  for (int k = 0; k < 8; k++) {
    int dl = gid * 8 + k;
    if (dl < ndst) {
      __half2* bp = (__half2*)(Bh + (size_t)(d0 + dl) * 64) + hl;
      float2 old = __half22float2(*bp);
      float inv = 1.f / (den[k] + 1e-16f);
      old.x += acc[k].x * inv;
      old.y += acc[k].y * inv;
      *bp = __float22half2_rn(old);
    }
  }
}

// ---------------- pooling ----------------
__global__ __launch_bounds__(256) void k_pool(
    const __half* __restrict__ H, const int* __restrict__ batch,
    float* __restrict__ pooled, int* __restrict__ cnt, int n) {
  int lane = threadIdx.x & 63;
  int w = threadIdx.x >> 6;
  int n0 = blockIdx.x * 64 + w * 16;
  float acc = 0.f;
  int cur = -1, nc = 0;
  for (int i = 0; i < 16; i++) {
    int node = n0 + i;
    if (node >= n) break;
    int g = batch[node];
    if (g != cur) {
      if (cur >= 0) {
        atomicAdd(&pooled[cur * 64 + lane], acc);
        if (lane == 0) atomicAdd(&cnt[cur], nc);
      }
      cur = g;
      acc = 0.f;
      nc = 0;
    }
    acc += __half2float(H[(size_t)node * 64 + lane]);
    nc++;
  }
  if (cur >= 0) {
    atomicAdd(&pooled[cur * 64 + lane], acc);
    if (lane == 0) atomicAdd(&cnt[cur], nc);
  }
}

__global__ void k_out(const float* __restrict__ pooled, const int* __restrict__ cnt,
                      const float* __restrict__ Wf, const float* __restrict__ bf,
                      float* __restrict__ out) {
  int g = blockIdx.x;
  int lane = threadIdx.x;
  int c = cnt[g];
  float cf = (float)(c > 1 ? c : 1);
  float mean = pooled[g * 64 + lane] / cf;
#pragma unroll
  for (int o = 0; o < OUTF; o++) {
    float p = wave_reduce_sum(mean * Wf[lane * OUTF + o]);
    if (lane == 0) out[g * OUTF + o] = p + bf[o];
  }
}

// ---------------- launch ----------------
extern "C" void kernel_launch(void* const* d_in, const int* in_sizes, int n_in,
                              void* d_out, int out_size, void* d_ws, size_t ws_size,
                              hipStream_t stream) {
  const float* x   = (const float*)d_in[0];
  const int* ei    = (const int*)d_in[1];
  const int* batch = (const int*)d_in[2];
  const float *Wq0 = (const float*)d_in[3],  *bq0 = (const float*)d_in[4];
  const float *Wk0 = (const float*)d_in[5],  *bk0 = (const float*)d_in[6];
  const float *Wv0 = (const float*)d_in[7],  *bv0 = (const float*)d_in[8];
  const float *Ws0 = (const float*)d_in[9],  *bs0 = (const float*)d_in[10];
  const float *Wqh = (const float*)d_in[11], *bqh = (const float*)d_in[12];
  const float *Wkh = (const float*)d_in[13], *bkh = (const float*)d_in[14];
  const float *Wvh = (const float*)d_in[15], *bvh = (const float*)d_in[16];
  const float *Wsh = (const float*)d_in[17], *bsh = (const float*)d_in[18];
  const float *Wf  = (const float*)d_in[19], *bf  = (const float*)d_in[20];

  __half* qh = (__half*)d_ws;
  __half* kh = qh + (size_t)NN * 64;
  __half* vh = kh + (size_t)NN * 64;
  __half* B0 = vh + (size_t)NN * 64;
  __half* B1 = B0 + (size_t)NN * 64;
  float* pooled = (float*)(B1 + (size_t)NN * 64);
  int* cnt     = (int*)(pooled + GG * 64);
  int* row_ptr = cnt + GG;
  int* col     = row_ptr + NN + 2;
  int* hblk    = col + EE;
  int* incl2   = hblk + LEN;
  int* bsum2   = incl2 + LEN;
  int* boff2   = bsum2 + 128;
  int* eoff    = boff2 + 128;
  int2* ebuf   = (int2*)((((uintptr_t)(eoff + LEN)) + 15) & ~(uintptr_t)15);

  hipMemsetAsync(pooled, 0, (GG * 64 + GG) * sizeof(float), stream);

  // bucketed CSR build (once per call; reused by all 4 layers)
  k_bh<<<EB, 256, 0, stream>>>(ei, hblk);
  int nb2 = (LEN + 1023) / 1024;
  k_scan1<<<nb2, 256, 0, stream>>>(hblk, incl2, bsum2, LEN);
  k_scan2<<<1, 64, 0, stream>>>(bsum2, boff2, nb2);
  k_eoff<<<(LEN + 255) / 256, 256, 0, stream>>>(incl2, boff2, hblk, eoff, LEN);
  k_binwrite<<<EB, 256, 0, stream>>>(ei, eoff, ebuf);
  k_bcsr<<<NBUK, 256, 0, stream>>>(ebuf, eoff, row_ptr, col, NN);

  int gg = (NN + 63) / 64;
  int ga = (NN + 63) / 64;   // 64 dsts per block

  // layer 0 (F_IN=16, fp32 input)
  k_gemm_mfma<FIN, float><<<gg, 256, 0, stream>>>(
      x, Wq0, bq0, Wk0, bk0, Wv0, bv0, Ws0, bs0, qh, kh, vh, B0, NN);
  k_fused<<<ga, 256, 0, stream>>>(qh, kh, vh, row_ptr, col, B0, NN);

  // hidden layers (H=64, fp16 h), ping-pong B0 <-> B1
  const __half* hin = B0;
  __half* hout = B1;
  for (int i = 0; i < NHID; i++) {
    k_gemm_mfma<HH, __half><<<gg, 256, 0, stream>>>(
        hin, Wqh + i * 4096, bqh + i * 64,
        Wkh + i * 4096, bkh + i * 64,
        Wvh + i * 4096, bvh + i * 64,
        Wsh + i * 4096, bsh + i * 64,
        qh, kh, vh, hout, NN);
    k_fused<<<ga, 256, 0, stream>>>(qh, kh, vh, row_ptr, col, hout, NN);
    __half* t = (__half*)hin; hin = hout; hout = t;
  }

  k_pool<<<(NN + 63) / 64, 256, 0, stream>>>(hin, batch, pooled, cnt, NN);
  k_out<<<GG, 64, 0, stream>>>(pooled, cnt, Wf, bf, (float*)d_out);
}

// Round 5
// 466.833 us; speedup vs baseline: 1.0325x; 1.0325x over previous
//
#include <hip/hip_runtime.h>
#include <hip/hip_fp16.h>
#include <math.h>
#include <stdint.h>
#include <type_traits>

#define NN   100000
#define EE   1200000
#define GG   128
#define FIN  16
#define HH   64
#define OUTF 5
#define NHID 3

#define CE   4096                       // edges per block in bucket phases
#define EB   ((EE + CE - 1) / CE)       // 293 edge-blocks
#define NBUK ((NN + 511) >> 9)          // 196 buckets of 512 nodes
#define LEN  (NBUK * EB)                // hblk/eoff length

#define SRCMASK 0x03FFFFFFu             // low 26 bits of packed col entry
#define FB_DST 32                       // dsts per fused block (R20)

typedef _Float16 f16x8 __attribute__((ext_vector_type(8)));
typedef _Float16 f16x2 __attribute__((ext_vector_type(2)));
typedef float f32x4 __attribute__((ext_vector_type(4)));

#if defined(__has_builtin)
#if __has_builtin(__builtin_amdgcn_fdot2)
#define HAVE_FDOT2 1
#endif
#endif

static __device__ __forceinline__ float dot8_f16(f16x8 a, f16x8 b) {
#ifdef HAVE_FDOT2
  float ds = 0.f;
#pragma unroll
  for (int u = 0; u < 4; u++) {
    f16x2 x = {a[2 * u], a[2 * u + 1]};
    f16x2 y = {b[2 * u], b[2 * u + 1]};
    ds = __builtin_amdgcn_fdot2(x, y, ds, false);
  }
  return ds;
#else
  float ds = 0.f;
#pragma unroll
  for (int u = 0; u < 8; u++) ds += (float)a[u] * (float)b[u];
  return ds;
#endif
}

// ---------------- wave helpers ----------------
static __device__ __forceinline__ float wave_reduce_sum(float p) {
#pragma unroll
  for (int m = 32; m >= 1; m >>= 1) p += __shfl_xor(p, m, 64);
  return p;
}

// ---------------- bucketed CSR build ----------------
__global__ void k_bh(const int* __restrict__ ei, int* __restrict__ hblk) {
  __shared__ int h[NBUK];
  int tid = threadIdx.x, blk = blockIdx.x;
  for (int i = tid; i < NBUK; i += 256) h[i] = 0;
  __syncthreads();
  int base = blk * CE;
  for (int i = tid; i < CE; i += 256) {
    int e = base + i;
    if (e < EE) atomicAdd(&h[ei[EE + e] >> 9], 1);
  }
  __syncthreads();
  for (int i = tid; i < NBUK; i += 256) hblk[i * EB + blk] = h[i];
}

__global__ void k_scan1(const int* __restrict__ in, int* __restrict__ incl,
                        int* __restrict__ bsum, int n) {
  __shared__ int sd[256];
  int t = threadIdx.x, blk = blockIdx.x;
  int base = blk * 1024 + t * 4;
  int v[4];
#pragma unroll
  for (int i = 0; i < 4; i++) v[i] = (base + i < n) ? in[base + i] : 0;
  int s = v[0] + v[1] + v[2] + v[3];
  sd[t] = s;
  __syncthreads();
  for (int off = 1; off < 256; off <<= 1) {
    int x = 0;
    if (t >= off) x = sd[t - off];
    __syncthreads();
    if (t >= off) sd[t] += x;
    __syncthreads();
  }
  int run = sd[t] - s;
#pragma unroll
  for (int i = 0; i < 4; i++) {
    run += v[i];
    if (base + i < n) incl[base + i] = run;
  }
  if (t == 255) bsum[blk] = sd[255];
}

__global__ void k_scan2(const int* __restrict__ bsum, int* __restrict__ boff, int nb) {
  if (threadIdx.x == 0 && blockIdx.x == 0) {
    int run = 0;
    for (int i = 0; i < nb; i++) { boff[i] = run; run += bsum[i]; }
  }
}

__global__ void k_eoff(const int* __restrict__ incl, const int* __restrict__ boff,
                       const int* __restrict__ hblk, int* __restrict__ eoff, int n) {
  int t = blockIdx.x * blockDim.x + threadIdx.x;
  if (t < n) eoff[t] = incl[t] + boff[t / 1024] - hblk[t];
}

__global__ void k_binwrite(const int* __restrict__ ei, const int* __restrict__ eoff,
                           int2* __restrict__ ebuf) {
  __shared__ int cur[NBUK];
  int tid = threadIdx.x, blk = blockIdx.x;
  for (int i = tid; i < NBUK; i += 256) cur[i] = eoff[i * EB + blk];
  __syncthreads();
  int base = blk * CE;
  for (int i = tid; i < CE; i += 256) {
    int e = base + i;
    if (e < EE) {
      int d = ei[EE + e];
      int s = ei[e];
      int p = atomicAdd(&cur[d >> 9], 1);
      ebuf[p] = make_int2(s, d);
    }
  }
}

// merged bdeg2 + binscatter: histogram -> scan -> row_ptr -> cursors ->
// scatter col. col entry packs dst-mod-64 into bits 26..31; src (<2^26)
// in low bits. Fused blocks are 64-grid-aligned (32 dsts), so dst-local
// decodes as (v>>26)&31.
__global__ void k_bcsr(const int2* __restrict__ ebuf, const int* __restrict__ eoff,
                       int* __restrict__ row_ptr, int* __restrict__ col, int n) {
  __shared__ int dl[512];
  __shared__ int ps[256];
  int b = blockIdx.x, tid = threadIdx.x;
  int d0 = b << 9;
  dl[tid] = 0; dl[tid + 256] = 0;
  __syncthreads();
  int s0 = eoff[b * EB];
  int s1 = (b + 1 < NBUK) ? eoff[(b + 1) * EB] : EE;
  for (int e = s0 + tid; e < s1; e += 256) atomicAdd(&dl[ebuf[e].y - d0], 1);
  __syncthreads();
  int a0 = dl[2 * tid], a1 = dl[2 * tid + 1];
  ps[tid] = a0 + a1;
  __syncthreads();
  for (int off = 1; off < 256; off <<= 1) {
    int x = 0;
    if (tid >= off) x = ps[tid - off];
    __syncthreads();
    if (tid >= off) ps[tid] += x;
    __syncthreads();
  }
  int epair = ps[tid] - (a0 + a1);     // exclusive prefix of this pair
  int r0 = s0 + epair;
  int r1 = r0 + a0;
  int i0 = d0 + 2 * tid;
  if (i0 <= n) row_ptr[i0] = r0;       // covers row_ptr[n] = EE
  if (i0 + 1 <= n) row_ptr[i0 + 1] = r1;
  __syncthreads();
  dl[2 * tid] = r0;                    // reuse histogram LDS as cursors
  dl[2 * tid + 1] = r1;
  __syncthreads();
  for (int e = s0 + tid; e < s1; e += 256) {
    int2 sd = ebuf[e];
    int p = atomicAdd(&dl[sd.y - d0], 1);
    col[p] = (int)(((unsigned)sd.x) | (((unsigned)sd.y & 63u) << 26));
  }
}

// ---------------- projections via MFMA (R18-proven epilogue) ----------------
template <int F, typename TIN>
__global__ __launch_bounds__(256) void k_gemm_mfma(
    const TIN* __restrict__ X,
    const float* __restrict__ Wq, const float* __restrict__ bq,
    const float* __restrict__ Wk, const float* __restrict__ bk,
    const float* __restrict__ Wv, const float* __restrict__ bv,
    const float* __restrict__ Ws, const float* __restrict__ bs,
    __half* __restrict__ qh, __half* __restrict__ kh, __half* __restrict__ vh,
    __half* __restrict__ Bh, int n) {
  constexpr int KH = (F + 31) / 32;
  constexpr int S = KH * 32 + 8;
  __shared__ _Float16 xs[64 * S];
  int tid = threadIdx.x;
  int lane = tid & 63;
  int wv = tid >> 6;
  int quad = lane >> 4;
  int li = lane & 15;
  int node0 = blockIdx.x * 64;

  if constexpr (std::is_same<TIN, float>::value) {
    constexpr int F4 = F / 4;
    constexpr int CNT = 64 * F4 / 256;
#pragma unroll
    for (int i = 0; i < CNT; i++) {
      int idx = tid + i * 256;
      int nd = idx / F4;
      int kb = (idx % F4) * 4;
      float4 p;
      if (node0 + nd < n) p = *(const float4*)(X + (size_t)(node0 + nd) * F + kb);
      else p = make_float4(0.f, 0.f, 0.f, 0.f);
      _Float16* d = xs + nd * S + kb;
      d[0] = (_Float16)p.x; d[1] = (_Float16)p.y;
      d[2] = (_Float16)p.z; d[3] = (_Float16)p.w;
    }
    if (F == 16) {  // zero-pad k in [16,32)
      int nd = tid >> 2;
      int kb = 16 + (tid & 3) * 4;
      _Float16* d = xs + nd * S + kb;
      d[0] = 0; d[1] = 0; d[2] = 0; d[3] = 0;
    }
  } else {
    constexpr int F8 = F / 8;
    constexpr int CNT = 64 * F8 / 256;
#pragma unroll
    for (int i = 0; i < CNT; i++) {
      int idx = tid + i * 256;
      int nd = idx / F8;
      int kb = (idx % F8) * 8;
      f16x8 p = {};
      if (node0 + nd < n)
        p = *(const f16x8*)((const _Float16*)X + (size_t)(node0 + nd) * F + kb);
      *(f16x8*)(xs + nd * S + kb) = p;
    }
  }

  const float* W; const float* bias;
  if (wv == 0)      { W = Wq; bias = bq; }
  else if (wv == 1) { W = Wk; bias = bk; }
  else if (wv == 2) { W = Wv; bias = bv; }
  else              { W = Ws; bias = bs; }

  f16x8 bf[4][KH];
#pragma unroll
  for (int ns = 0; ns < 4; ns++)
#pragma unroll
    for (int kh2 = 0; kh2 < KH; kh2++)
#pragma unroll
      for (int j = 0; j < 8; j++) {
        int kidx = kh2 * 32 + quad * 8 + j;
        bf[ns][kh2][j] = (kidx < F)
            ? (_Float16)W[(size_t)kidx * 64 + ns * 16 + li] : (_Float16)0.f;
      }
  float blv[4];
#pragma unroll
  for (int ns = 0; ns < 4; ns++) blv[ns] = bias[ns * 16 + li];

  __syncthreads();

  f16x8 af[4][KH];
#pragma unroll
  for (int ms = 0; ms < 4; ms++)
#pragma unroll
    for (int kh2 = 0; kh2 < KH; kh2++)
      af[ms][kh2] = *(const f16x8*)(xs + (ms * 16 + li) * S + kh2 * 32 + quad * 8);

  f32x4 acc[4][4];
#pragma unroll
  for (int ms = 0; ms < 4; ms++)
#pragma unroll
    for (int ns = 0; ns < 4; ns++) {
      float b = blv[ns];
      acc[ms][ns] = (f32x4){b, b, b, b};
    }
#pragma unroll
  for (int kh2 = 0; kh2 < KH; kh2++)
#pragma unroll
    for (int ms = 0; ms < 4; ms++)
#pragma unroll
      for (int ns = 0; ns < 4; ns++)
        acc[ms][ns] = __builtin_amdgcn_mfma_f32_16x16x32_f16(
            af[ms][kh2], bf[ns][kh2], acc[ms][ns], 0, 0, 0);

  __half* outh = (wv == 0) ? qh : (wv == 1) ? kh : (wv == 2) ? vh : Bh;
#pragma unroll
  for (int ms = 0; ms < 4; ms++)
#pragma unroll
    for (int ns = 0; ns < 4; ns++) {
      int colc = ns * 16 + li;
#pragma unroll
      for (int r = 0; r < 4; r++) {
        int node = node0 + ms * 16 + quad * 4 + r;
        if (node < n)
          outh[(size_t)node * 64 + colc] = __float2half(acc[ms][ns][r]);
      }
    }
}

// ---------------- fused attention, two internal phases (R20) ----------------
// Block = 32 consecutive dsts, 128 threads (2 waves). Grid 3125 blocks
// -> ~12 blocks/CU (R19's 64-dst/256-thr blocks gave only 6.1/CU and
// capped occupancy at 53% on this latency-bound gather kernel).
// Phase A (16 groups x 8 lanes): dst-local from col bits 26..31, fdot2
// dot, 3 shfl reduce, exp -> ws[i].y; manually unrolled x2 for deeper
// gather pipelining. Phase B (4 groups x 32 lanes, 8 dsts each):
// register accumulators, coalesced v rows, one b64 LDS read per edge.
__global__ __launch_bounds__(128) void k_fused(
    const __half* __restrict__ qh, const __half* __restrict__ kh,
    const __half* __restrict__ vh, const int* __restrict__ row_ptr,
    const int* __restrict__ col, __half* __restrict__ Bh, int n) {
  __shared__ int2 ws[512];             // .x = packed col, .y = weight bits
  __shared__ int rpl[FB_DST + 1];
  int tid = threadIdx.x;
  int d0 = blockIdx.x * FB_DST;
  int ndst = n - d0; if (ndst > FB_DST) ndst = FB_DST;

  if (tid < FB_DST + 1) {
    int dd = d0 + tid; if (dd > n) dd = n;
    rpl[tid] = row_ptr[dd];
  }
  __syncthreads();
  int e0 = rpl[0], e1 = rpl[ndst];

  int gid = tid >> 5, hl = tid & 31;   // phase B: 4 groups x 32 lanes
  int ag = tid >> 3, aj = tid & 7;     // phase A: 16 groups x 8 lanes

  float2 acc[8];
  float den[8];
#pragma unroll
  for (int k = 0; k < 8; k++) { acc[k] = make_float2(0.f, 0.f); den[k] = 0.f; }

  for (int c0 = e0; c0 < e1; c0 += 512) {
    int cn = e1 - c0; if (cn > 512) cn = 512;
    // stage col chunk (coalesced)
#pragma unroll
    for (int s = 0; s < 4; s++) {
      int i = tid + s * 128;
      if (i < cn) ws[i].x = col[c0 + i];
    }
    __syncthreads();

    // ---- phase A: scores (unrolled x2 per group) ----
    {
      int i = ag;
      for (; i + 16 < cn; i += 32) {
        unsigned v0 = (unsigned)ws[i].x;
        unsigned v1 = (unsigned)ws[i + 16].x;
        int src0 = (int)(v0 & SRCMASK), dl0 = (int)((v0 >> 26) & 31u);
        int src1 = (int)(v1 & SRCMASK), dl1 = (int)((v1 >> 26) & 31u);
        f16x8 kv0 = *(const f16x8*)((const _Float16*)kh + (size_t)src0 * 64 + aj * 8);
        f16x8 qv0 = *(const f16x8*)((const _Float16*)qh + (size_t)(d0 + dl0) * 64 + aj * 8);
        f16x8 kv1 = *(const f16x8*)((const _Float16*)kh + (size_t)src1 * 64 + aj * 8);
        f16x8 qv1 = *(const f16x8*)((const _Float16*)qh + (size_t)(d0 + dl1) * 64 + aj * 8);
        float ds0 = dot8_f16(qv0, kv0);
        float ds1 = dot8_f16(qv1, kv1);
        ds0 += __shfl_xor(ds0, 1, 64); ds1 += __shfl_xor(ds1, 1, 64);
        ds0 += __shfl_xor(ds0, 2, 64); ds1 += __shfl_xor(ds1, 2, 64);
        ds0 += __shfl_xor(ds0, 4, 64); ds1 += __shfl_xor(ds1, 4, 64);
        if (aj == 0) {
          ws[i].y      = __float_as_int(__expf(fminf(ds0 * 0.125f, 60.f)));
          ws[i + 16].y = __float_as_int(__expf(fminf(ds1 * 0.125f, 60.f)));
        }
      }
      if (i < cn) {
        unsigned v0 = (unsigned)ws[i].x;
        int src0 = (int)(v0 & SRCMASK), dl0 = (int)((v0 >> 26) & 31u);
        f16x8 kv0 = *(const f16x8*)((const _Float16*)kh + (size_t)src0 * 64 + aj * 8);
        f16x8 qv0 = *(const f16x8*)((const _Float16*)qh + (size_t)(d0 + dl0) * 64 + aj * 8);
        float ds0 = dot8_f16(qv0, kv0);
        ds0 += __shfl_xor(ds0, 1, 64);
        ds0 += __shfl_xor(ds0, 2, 64);
        ds0 += __shfl_xor(ds0, 4, 64);
        if (aj == 0) ws[i].y = __float_as_int(__expf(fminf(ds0 * 0.125f, 60.f)));
      }
    }
    __syncthreads();

    // ---- phase B: aggregate; group gid owns dsts gid*8 .. gid*8+7 ----
#pragma unroll
    for (int k = 0; k < 8; k++) {
      int dl = gid * 8 + k;
      if (dl < ndst) {
        int lo2 = rpl[dl];     if (lo2 < c0) lo2 = c0;
        int hi2 = rpl[dl + 1]; if (hi2 > c0 + cn) hi2 = c0 + cn;
        int i = lo2 - c0, iend = hi2 - c0;
        for (; i + 2 <= iend; i += 2) {
          int2 p0 = ws[i], p1 = ws[i + 1];
          float w0 = __int_as_float(p0.y); int s0 = p0.x & (int)SRCMASK;
          float w1 = __int_as_float(p1.y); int s1 = p1.x & (int)SRCMASK;
          float2 f0 = __half22float2(*(const __half2*)(vh + (size_t)s0 * 64 + hl * 2));
          float2 f1 = __half22float2(*(const __half2*)(vh + (size_t)s1 * 64 + hl * 2));
          acc[k].x = fmaf(w0, f0.x, acc[k].x); acc[k].y = fmaf(w0, f0.y, acc[k].y);
          acc[k].x = fmaf(w1, f1.x, acc[k].x); acc[k].y = fmaf(w1, f1.y, acc[k].y);
          den[k] += w0 + w1;
        }
        if (i < iend) {
          int2 p0 = ws[i];
          float w0 = __int_as_float(p0.y); int s0 = p0.x & (int)SRCMASK;
          float2 f0 = __half22float2(*(const __half2*)(vh + (size_t)s0 * 64 + hl * 2));
          acc[k].x = fmaf(w0, f0.x, acc[k].x); acc[k].y = fmaf(w0, f0.y, acc[k].y);
          den[k] += w0;
        }
      }
    }
    __syncthreads();   // before next chunk overwrites ws
  }

  // write out (B pre-holds the skip term)
#pragma unroll
  for (int k = 0; k < 8; k++) {
    int dl = gid * 8 + k;
    if (dl < ndst) {
      __half2* bp = (__half2*)(Bh + (size_t)(d0 + dl) * 64) + hl;
      float2 old = __half22float2(*bp);
      float inv = 1.f / (den[k] + 1e-16f);
      old.x += acc[k].x * inv;
      old.y += acc[k].y * inv;
      *bp = __float22half2_rn(old);
    }
  }
}

// ---------------- pooling ----------------
__global__ __launch_bounds__(256) void k_pool(
    const __half* __restrict__ H, const int* __restrict__ batch,
    float* __restrict__ pooled, int* __restrict__ cnt, int n) {
  int lane = threadIdx.x & 63;
  int w = threadIdx.x >> 6;
  int n0 = blockIdx.x * 64 + w * 16;
  float acc = 0.f;
  int cur = -1, nc = 0;
  for (int i = 0; i < 16; i++) {
    int node = n0 + i;
    if (node >= n) break;
    int g = batch[node];
    if (g != cur) {
      if (cur >= 0) {
        atomicAdd(&pooled[cur * 64 + lane], acc);
        if (lane == 0) atomicAdd(&cnt[cur], nc);
      }
      cur = g;
      acc = 0.f;
      nc = 0;
    }
    acc += __half2float(H[(size_t)node * 64 + lane]);
    nc++;
  }
  if (cur >= 0) {
    atomicAdd(&pooled[cur * 64 + lane], acc);
    if (lane == 0) atomicAdd(&cnt[cur], nc);
  }
}

__global__ void k_out(const float* __restrict__ pooled, const int* __restrict__ cnt,
                      const float* __restrict__ Wf, const float* __restrict__ bf,
                      float* __restrict__ out) {
  int g = blockIdx.x;
  int lane = threadIdx.x;
  int c = cnt[g];
  float cf = (float)(c > 1 ? c : 1);
  float mean = pooled[g * 64 + lane] / cf;
#pragma unroll
  for (int o = 0; o < OUTF; o++) {
    float p = wave_reduce_sum(mean * Wf[lane * OUTF + o]);
    if (lane == 0) out[g * OUTF + o] = p + bf[o];
  }
}

// ---------------- launch ----------------
extern "C" void kernel_launch(void* const* d_in, const int* in_sizes, int n_in,
                              void* d_out, int out_size, void* d_ws, size_t ws_size,
                              hipStream_t stream) {
  const float* x   = (const float*)d_in[0];
  const int* ei    = (const int*)d_in[1];
  const int* batch = (const int*)d_in[2];
  const float *Wq0 = (const float*)d_in[3],  *bq0 = (const float*)d_in[4];
  const float *Wk0 = (const float*)d_in[5],  *bk0 = (const float*)d_in[6];
  const float *Wv0 = (const float*)d_in[7],  *bv0 = (const float*)d_in[8];
  const float *Ws0 = (const float*)d_in[9],  *bs0 = (const float*)d_in[10];
  const float *Wqh = (const float*)d_in[11], *bqh = (const float*)d_in[12];
  const float *Wkh = (const float*)d_in[13], *bkh = (const float*)d_in[14];
  const float *Wvh = (const float*)d_in[15], *bvh = (const float*)d_in[16];
  const float *Wsh = (const float*)d_in[17], *bsh = (const float*)d_in[18];
  const float *Wf  = (const float*)d_in[19], *bf  = (const float*)d_in[20];

  __half* qh = (__half*)d_ws;
  __half* kh = qh + (size_t)NN * 64;
  __half* vh = kh + (size_t)NN * 64;
  __half* B0 = vh + (size_t)NN * 64;
  __half* B1 = B0 + (size_t)NN * 64;
  float* pooled = (float*)(B1 + (size_t)NN * 64);
  int* cnt     = (int*)(pooled + GG * 64);
  int* row_ptr = cnt + GG;
  int* col     = row_ptr + NN + 2;
  int* hblk    = col + EE;
  int* incl2   = hblk + LEN;
  int* bsum2   = incl2 + LEN;
  int* boff2   = bsum2 + 128;
  int* eoff    = boff2 + 128;
  int2* ebuf   = (int2*)((((uintptr_t)(eoff + LEN)) + 15) & ~(uintptr_t)15);

  hipMemsetAsync(pooled, 0, (GG * 64 + GG) * sizeof(float), stream);

  // bucketed CSR build (once per call; reused by all 4 layers)
  k_bh<<<EB, 256, 0, stream>>>(ei, hblk);
  int nb2 = (LEN + 1023) / 1024;
  k_scan1<<<nb2, 256, 0, stream>>>(hblk, incl2, bsum2, LEN);
  k_scan2<<<1, 64, 0, stream>>>(bsum2, boff2, nb2);
  k_eoff<<<(LEN + 255) / 256, 256, 0, stream>>>(incl2, boff2, hblk, eoff, LEN);
  k_binwrite<<<EB, 256, 0, stream>>>(ei, eoff, ebuf);
  k_bcsr<<<NBUK, 256, 0, stream>>>(ebuf, eoff, row_ptr, col, NN);

  int gg = (NN + 63) / 64;
  int ga = (NN + FB_DST - 1) / FB_DST;  // 32 dsts per block, 128 threads

  // layer 0 (F_IN=16, fp32 input)
  k_gemm_mfma<FIN, float><<<gg, 256, 0, stream>>>(
      x, Wq0, bq0, Wk0, bk0, Wv0, bv0, Ws0, bs0, qh, kh, vh, B0, NN);
  k_fused<<<ga, 128, 0, stream>>>(qh, kh, vh, row_ptr, col, B0, NN);

  // hidden layers (H=64, fp16 h), ping-pong B0 <-> B1
  const __half* hin = B0;
  __half* hout = B1;
  for (int i = 0; i < NHID; i++) {
    k_gemm_mfma<HH, __half><<<gg, 256, 0, stream>>>(
        hin, Wqh + i * 4096, bqh + i * 64,
        Wkh + i * 4096, bkh + i * 64,
        Wvh + i * 4096, bvh + i * 64,
        Wsh + i * 4096, bsh + i * 64,
        qh, kh, vh, hout, NN);
    k_fused<<<ga, 128, 0, stream>>>(qh, kh, vh, row_ptr, col, hout, NN);
    __half* t = (__half*)hin; hin = hout; hout = t;
  }

  k_pool<<<(NN + 63) / 64, 256, 0, stream>>>(hin, batch, pooled, cnt, NN);
  k_out<<<GG, 64, 0, stream>>>(pooled, cnt, Wf, bf, (float*)d_out);
}